// Round 2
// baseline (418.917 us; speedup 1.0000x reference)
//
#include <hip/hip_runtime.h>

// Problem constants (from reference)
#define BB 4
#define CC 256
#define XX 256
#define YY 256
#define NCELLS (BB * XX * YY)   // 262144 cells, 1 MiB of int32

#define YCH 32                  // y-cells staged per chunk (32 rows x 1KB = 32 KB LDS)
#define NYCH (YY / YCH)         // 8 chunks

// ---------------------------------------------------------------------------
// Kernel 1: fill the cell->row index grid with -1 (int4-vectorized, coalesced)
// ---------------------------------------------------------------------------
__global__ void k_fill_idx(int4* __restrict__ idx4) {
    int i = blockIdx.x * blockDim.x + threadIdx.x;   // NCELLS/4 threads exactly
    idx4[i] = make_int4(-1, -1, -1, -1);
}

// ---------------------------------------------------------------------------
// Kernel 2: scatter row index n into idx[cell]  (coords unique => no races)
// ---------------------------------------------------------------------------
__global__ void k_scatter_idx(const int* __restrict__ coords,
                              int* __restrict__ idx, int n) {
    int i = blockIdx.x * blockDim.x + threadIdx.x;
    if (i >= n) return;
    int b = coords[i * 3 + 0];
    int x = coords[i * 3 + 1];
    int y = coords[i * 3 + 2];
    // mode="drop": out-of-range coords are dropped
    if ((unsigned)b < BB && (unsigned)x < XX && (unsigned)y < YY) {
        idx[(b * XX + x) * YY + y] = i;
    }
}

// ---------------------------------------------------------------------------
// Kernel 3: whole-row burst gather.
// Theory: feats reads were random 128B lines at HBM (row-activation bound).
// Fix: ONE wave instruction = ONE whole 1KB feats row (64 lanes x float4,
// 1KB-aligned, 8 sequential lines) -> HBM sees 1KB bursts, one row
// activation per KB instead of per 128B.
//
// Block = (b,x) slice, 256 threads (4 waves), y-chunks of 32:
//   STAGE: wave w fetches rows y0+8w..y0+8w+7, one row per instruction,
//          writes LDS [32][256] row-major (dense b128 writes, conflict-free,
//          column-XOR-swizzled so the transposed drain reads are 2-way).
//   DRAIN: lane builds float4 of 4 consecutive y for plane c via 4
//          ds_read_b32 (swizzle => 2 lanes/bank = free, m136), stores
//          1KB per wave instruction (8 planes x 128B full lines).
// Swizzle: element (y,c) lives at lds[y][c ^ S(y)], S(y) = ((y>>1)&7)<<2.
//   - stage: S constant per row -> columns stay a dense 16B-aligned perm.
//   - drain instr: bank = (c ^ S) & 31 has 3 varying bits from g and 2 from
//     m&3 -> 32 distinct banks, 2 lanes each = conflict-free.
// ---------------------------------------------------------------------------
__global__ __launch_bounds__(256, 4) void k_gather_out(
        const float4* __restrict__ feats4,
        const int*    __restrict__ idx,
        float*        __restrict__ out) {
    __shared__ int   rowid[YY];            // 1 KB
    __shared__ float lds[YCH][CC];         // 32 KB staging tile

    const int bx = blockIdx.x;             // 0 .. B*X-1
    const int t  = threadIdx.x;            // 0 .. 255
    const int b  = bx >> 8;
    const int x  = bx & 255;

    rowid[t] = idx[bx * YY + t];           // coalesced, L2-resident (1 MiB)
    __syncthreads();

    const int lane = t & 63;
    const int w    = t >> 6;               // wave id 0..3
    const int g    = lane >> 3;            // 0..7
    const int m    = lane & 7;             // 0..7

    const size_t out_base = ((size_t)b * CC * XX + x) * YY;

    for (int yc = 0; yc < NYCH; ++yc) {
        const int y0 = yc * YCH;

        // ---- STAGE: 8 whole-row loads per wave, issued back-to-back ----
        float4 v[8];
        #pragma unroll
        for (int j = 0; j < 8; ++j) {
            const int yl = w * 8 + j;                  // 0..31 across waves
            const int r  = rowid[y0 + yl];             // LDS broadcast
            const bool valid = (r >= 0);
            v[j] = feats4[(size_t)(valid ? r : 0) * (CC / 4) + lane];
            if (!valid) { v[j].x = 0.f; v[j].y = 0.f; v[j].z = 0.f; v[j].w = 0.f; }
        }
        #pragma unroll
        for (int j = 0; j < 8; ++j) {
            const int yl = w * 8 + j;
            const int S  = ((yl >> 1) & 7) << 2;       // column swizzle
            *(float4*)&lds[yl][(4 * lane) ^ S] = v[j]; // 16B-aligned dense write
        }
        __syncthreads();

        // ---- DRAIN: 8 stores per thread, 1KB per wave instruction ----
        #pragma unroll
        for (int k = 0; k < 8; ++k) {
            const int c = k * 32 + w * 8 + g;          // covers 0..255 once
            float4 o;
            {
                const int y0l = 4 * m;
                o.x = lds[y0l + 0][c ^ ((((y0l + 0) >> 1) & 7) << 2)];
                o.y = lds[y0l + 1][c ^ ((((y0l + 1) >> 1) & 7) << 2)];
                o.z = lds[y0l + 2][c ^ ((((y0l + 2) >> 1) & 7) << 2)];
                o.w = lds[y0l + 3][c ^ ((((y0l + 3) >> 1) & 7) << 2)];
            }
            *(float4*)&out[out_base + (size_t)c * (XX * YY) + y0 + 4 * m] = o;
        }
        __syncthreads();
    }
}

extern "C" void kernel_launch(void* const* d_in, const int* in_sizes, int n_in,
                              void* d_out, int out_size, void* d_ws, size_t ws_size,
                              hipStream_t stream) {
    const float* feats  = (const float*)d_in[0];   // [N, 256] fp32
    const int*   coords = (const int*)d_in[1];     // [N, 3]   int32
    int n = in_sizes[1] / 3;                       // N = 200000

    int*   idx = (int*)d_ws;                       // 1 MiB scratch
    float* out = (float*)d_out;

    // 1) idx = -1 everywhere (65536 int4 elements)
    k_fill_idx<<<NCELLS / 4 / 256, 256, 0, stream>>>((int4*)idx);

    // 2) scatter row ids into occupied cells
    k_scatter_idx<<<(n + 255) / 256, 256, 0, stream>>>(coords, idx, n);

    // 3) whole-row burst gather: every output element written exactly once
    k_gather_out<<<BB * XX, 256, 0, stream>>>((const float4*)feats, idx, out);
}